// Round 1
// baseline (1068.733 us; speedup 1.0000x reference)
//
#include <hip/hip_runtime.h>

typedef unsigned short u16;
typedef float f32x4 __attribute__((ext_vector_type(4)));
typedef u16   u16x4 __attribute__((ext_vector_type(4)));
typedef u16   u16x8 __attribute__((ext_vector_type(8)));
typedef __bf16 bf16x8 __attribute__((ext_vector_type(8)));

static __device__ __forceinline__ u16 f2bf(float x) {
    unsigned int u = __builtin_bit_cast(unsigned int, x);
    u = (u + 0x7FFFu + ((u >> 16) & 1u)) >> 16;
    return (u16)u;
}
static __device__ __forceinline__ bf16x8 as_bf(u16x8 v) { return __builtin_bit_cast(bf16x8, v); }

// ---------------------------------------------------------------------------
// Kernel 1: W [1024 d_in][1024 d_out] fp32  ->  Wt [mat][1024 d_out][1024 d_in] bf16
// ---------------------------------------------------------------------------
__global__ __launch_bounds__(256) void wt_kernel(const float* __restrict__ Wq,
                                                 const float* __restrict__ Wk,
                                                 const float* __restrict__ Wv,
                                                 u16* __restrict__ Wt) {
    __shared__ float tile[64][65];
    const int mat = blockIdx.z;
    const float* W = (mat == 0) ? Wq : ((mat == 1) ? Wk : Wv);
    const int bx = blockIdx.x, by = blockIdx.y;   // bx: d_out tile, by: d_in tile
    const int tid = threadIdx.x;
#pragma unroll
    for (int i = 0; i < 16; ++i) {
        int idx = i * 256 + tid;
        int r = idx >> 6, c = idx & 63;
        tile[r][c] = W[(by * 64 + r) * 1024 + bx * 64 + c];
    }
    __syncthreads();
#pragma unroll
    for (int i = 0; i < 16; ++i) {
        int idx = i * 256 + tid;
        int r = idx >> 6, c = idx & 63;
        Wt[mat * 1048576 + (bx * 64 + r) * 1024 + by * 64 + c] = f2bf(tile[c][r]);
    }
}

// ---------------------------------------------------------------------------
// Kernel 2: QKV GEMM.  C[16384][3072] = X[16384][1024](fp32) * Wt^T (Wt: [3072][1024] bf16)
// Q,K written row-major bf16 [16384][1024]; V written TRANSPOSED per batch: Vt[b][1024][4096] bf16
// 128x128 tile, BK=64, 4 waves, 16x16x32 MFMA, XOR-swizzled LDS.
// ---------------------------------------------------------------------------
__global__ __launch_bounds__(256, 3) void qkv_gemm(const float* __restrict__ X,
                                                   const u16* __restrict__ Wt,
                                                   u16* __restrict__ Qo,
                                                   u16* __restrict__ Ko,
                                                   u16* __restrict__ Vto) {
    __shared__ u16 As[128 * 64];
    __shared__ u16 Bs[128 * 64];
    const int bid = blockIdx.x;
    const int swz = (bid & 7) * 384 + (bid >> 3);      // XCD swizzle, 3072 % 8 == 0
    const int bm = swz / 24, bn = swz % 24;
    const int tid = threadIdx.x;
    const int w = tid >> 6, l = tid & 63, lg = l >> 4, lr = l & 15;
    const int wr = w >> 1, wc = w & 1;

    const f32x4 z4 = {0.f, 0.f, 0.f, 0.f};
    f32x4 acc[4][4];
#pragma unroll
    for (int m = 0; m < 4; ++m)
#pragma unroll
        for (int n = 0; n < 4; ++n) acc[m][n] = z4;

    for (int kb = 0; kb < 16; ++kb) {
        __syncthreads();
        // stage A (fp32 -> bf16, swizzled)
#pragma unroll
        for (int i = 0; i < 4; ++i) {
            int cid = i * 256 + tid;
            int row = cid >> 3, c8 = cid & 7;
            const float* src = X + (bm * 128 + row) * 1024 + kb * 64 + c8 * 8;
            f32x4 v0 = *(const f32x4*)(src);
            f32x4 v1 = *(const f32x4*)(src + 4);
            u16x8 t;
            t[0] = f2bf(v0[0]); t[1] = f2bf(v0[1]); t[2] = f2bf(v0[2]); t[3] = f2bf(v0[3]);
            t[4] = f2bf(v1[0]); t[5] = f2bf(v1[1]); t[6] = f2bf(v1[2]); t[7] = f2bf(v1[3]);
            *(u16x8*)(&As[row * 64 + ((c8 ^ (row & 7)) << 3)]) = t;
        }
        // stage B (bf16 copy, swizzled)
#pragma unroll
        for (int i = 0; i < 4; ++i) {
            int cid = i * 256 + tid;
            int row = cid >> 3, c8 = cid & 7;
            u16x8 v = *(const u16x8*)(Wt + (bn * 128 + row) * 1024 + kb * 64 + c8 * 8);
            *(u16x8*)(&Bs[row * 64 + ((c8 ^ (row & 7)) << 3)]) = v;
        }
        __syncthreads();
#pragma unroll
        for (int kk = 0; kk < 2; ++kk) {
            bf16x8 af[4], bfr[4];
#pragma unroll
            for (int m = 0; m < 4; ++m) {
                int row = wr * 64 + m * 16 + lr;
                af[m] = as_bf(*(const u16x8*)(&As[row * 64 + (((kk * 4 + lg) ^ (lr & 7)) << 3)]));
            }
#pragma unroll
            for (int n = 0; n < 4; ++n) {
                int row = wc * 64 + n * 16 + lr;
                bfr[n] = as_bf(*(const u16x8*)(&Bs[row * 64 + (((kk * 4 + lg) ^ (lr & 7)) << 3)]));
            }
#pragma unroll
            for (int m = 0; m < 4; ++m)
#pragma unroll
                for (int n = 0; n < 4; ++n)
                    acc[m][n] = __builtin_amdgcn_mfma_f32_16x16x32_bf16(af[m], bfr[n], acc[m][n], 0, 0, 0);
        }
    }
    // epilogue
    const int row0 = bm * 128 + wr * 64;
    const int col0 = bn * 128 + wc * 64;
#pragma unroll
    for (int m = 0; m < 4; ++m) {
#pragma unroll
        for (int n = 0; n < 4; ++n) {
            int col = col0 + n * 16 + lr;
            int mat = col >> 10;
            int cg = col & 1023;
            int row = row0 + m * 16 + lg * 4;
            if (mat == 2) {
                int b = row >> 12, s = row & 4095;
                u16x4 v;
                v[0] = f2bf(acc[m][n][0]); v[1] = f2bf(acc[m][n][1]);
                v[2] = f2bf(acc[m][n][2]); v[3] = f2bf(acc[m][n][3]);
                *(u16x4*)(Vto + b * 4194304 + cg * 4096 + s) = v;
            } else {
                u16* P = mat ? Ko : Qo;
#pragma unroll
                for (int r = 0; r < 4; ++r) P[(row + r) * 1024 + cg] = f2bf(acc[m][n][r]);
            }
        }
    }
}

// ---------------------------------------------------------------------------
// Kernel 3: flash attention.
// Block: batch b, 64 q-rows. 8 waves. Wave w: unique 16-key slice for QK^T (S^T = K*Q^T),
// owns d-cols [w*128, w*128+128) of O^T for PV (A = V^T contiguous from global).
// Online softmax with defer-max (THR = 8/ln2 in log2 domain).
// ---------------------------------------------------------------------------
__global__ __launch_bounds__(512, 2) void attn_kernel(const u16* __restrict__ Qg,
                                                      const u16* __restrict__ Kg,
                                                      const u16* __restrict__ Vtg,
                                                      float* __restrict__ Out) {
    __shared__ u16 q_lds[64 * 1024];   // 128 KB, XOR-swizzled rows
    __shared__ u16 p_lds[64 * 128];    // 16 KB, XOR-swizzled rows
    __shared__ float pm[8 * 64];
    __shared__ float pl[8 * 64];
    __shared__ float mnew_s[64];
    __shared__ float alph_s[64];
    __shared__ float lrun_s[64];
    __shared__ int flag_s;

    const int bid = blockIdx.x;
    const int b = bid >> 6, qt = bid & 63;
    const int q0 = qt * 64;
    const int tid = threadIdx.x;
    const int w = tid >> 6, l = tid & 63, lg = l >> 4, lr = l & 15;

    // stage Q tile (once per block), swizzled
#pragma unroll
    for (int i = 0; i < 16; ++i) {
        int cid = i * 512 + tid;
        int row = cid >> 7, ch = cid & 127;
        u16x8 v = *(const u16x8*)(Qg + (((b << 12) + q0 + row) << 10) + ch * 8);
        *(u16x8*)(&q_lds[(row << 10) + ((ch ^ (row & 7)) << 3)]) = v;
    }

    const f32x4 z4 = {0.f, 0.f, 0.f, 0.f};
    f32x4 o[4][8];
#pragma unroll
    for (int qf = 0; qf < 4; ++qf)
#pragma unroll
        for (int df = 0; df < 8; ++df) o[qf][df] = z4;

    float m_run = -1e30f, l_run = 0.f, a_prev = 1.f;  // live on wave 0 (lane l <-> q row l)
    const float kscale = 0.045084220027780106f;       // log2(e)/32

    __syncthreads();

    for (int t = 0; t < 32; ++t) {
        const int k0 = t << 7;
        // wave0: fold previous tile's partial sums into running denominator
        if (w == 0 && t > 0) {
            float s_ = 0.f;
#pragma unroll
            for (int ww = 0; ww < 8; ++ww) s_ += pl[ww * 64 + l];
            l_run = l_run * a_prev + s_;
        }
        // ---- S^T = K * Q^T ----
        f32x4 sacc[4] = {z4, z4, z4, z4};
        const u16* kptr = Kg + (((b << 12) + k0 + w * 16 + lr) << 10) + lg * 8;
#pragma unroll
        for (int kb = 0; kb < 32; ++kb) {
            bf16x8 a = *(const bf16x8*)(kptr + kb * 32);
#pragma unroll
            for (int qf = 0; qf < 4; ++qf) {
                int row = qf * 16 + lr;
                bf16x8 bq = as_bf(*(const u16x8*)(&q_lds[(row << 10) + (((kb * 4 + lg) ^ (row & 7)) << 3)]));
                sacc[qf] = __builtin_amdgcn_mfma_f32_16x16x32_bf16(a, bq, sacc[qf], 0, 0, 0);
            }
        }
        float sp[4][4];
#pragma unroll
        for (int qf = 0; qf < 4; ++qf)
#pragma unroll
            for (int r = 0; r < 4; ++r) sp[qf][r] = sacc[qf][r] * kscale;

        // per-wave partial max per q
#pragma unroll
        for (int qf = 0; qf < 4; ++qf) {
            float v = fmaxf(fmaxf(sp[qf][0], sp[qf][1]), fmaxf(sp[qf][2], sp[qf][3]));
            v = fmaxf(v, __shfl_xor(v, 16, 64));
            v = fmaxf(v, __shfl_xor(v, 32, 64));
            if (lg == 0) pm[w * 64 + qf * 16 + lr] = v;
        }
        __syncthreads();
        if (w == 0) {
            float mt = pm[l];
#pragma unroll
            for (int ww = 1; ww < 8; ++ww) mt = fmaxf(mt, pm[ww * 64 + l]);
            bool resc = mt > m_run + 11.5f;   // defer-max threshold (8 nats)
            float mn = resc ? mt : m_run;
            float al = resc ? exp2f(m_run - mn) : 1.0f;
            mnew_s[l] = mn;
            alph_s[l] = al;
            m_run = mn;
            a_prev = al;
            unsigned long long bb = __ballot(al != 1.0f);
            if (l == 0) flag_s = (bb != 0ull) ? 1 : 0;
        }
        __syncthreads();
        const int fl = flag_s;
#pragma unroll
        for (int qf = 0; qf < 4; ++qf) {
            const int q = qf * 16 + lr;
            float mn = mnew_s[q];
            float p0 = exp2f(sp[qf][0] - mn);
            float p1 = exp2f(sp[qf][1] - mn);
            float p2 = exp2f(sp[qf][2] - mn);
            float p3 = exp2f(sp[qf][3] - mn);
            float sv = (p0 + p1) + (p2 + p3);
            sv += __shfl_xor(sv, 16, 64);
            sv += __shfl_xor(sv, 32, 64);
            if (lg == 0) pl[w * 64 + qf * 16 + lr] = sv;
            u16x4 pk;
            pk[0] = f2bf(p0); pk[1] = f2bf(p1); pk[2] = f2bf(p2); pk[3] = f2bf(p3);
            int byteoff = (q << 8) + ((w * 32 + lg * 8) ^ ((q & 7) << 4));
            *(u16x4*)((char*)p_lds + byteoff) = pk;
            if (fl) {
                float al = alph_s[q];
#pragma unroll
                for (int df = 0; df < 8; ++df) o[qf][df] *= al;
            }
        }
        __syncthreads();
        // ---- PV: O^T += V^T * P^T ----
        const u16* vbase = Vtg + b * 4194304 + k0;
#pragma unroll
        for (int ks = 0; ks < 4; ++ks) {
            bf16x8 av[8];
#pragma unroll
            for (int df = 0; df < 8; ++df)
                av[df] = *(const bf16x8*)(vbase + (w * 128 + df * 16 + lr) * 4096 + ks * 32 + lg * 8);
#pragma unroll
            for (int qf = 0; qf < 4; ++qf) {
                const int q = qf * 16 + lr;
                bf16x8 bp = as_bf(*(const u16x8*)((char*)p_lds + (q << 8) + ((ks * 64 + lg * 16) ^ ((q & 7) << 4))));
#pragma unroll
                for (int df = 0; df < 8; ++df)
                    o[qf][df] = __builtin_amdgcn_mfma_f32_16x16x32_bf16(av[df], bp, o[qf][df], 0, 0, 0);
            }
        }
        __syncthreads();
    }
    // epilogue: final denominator, normalize, store fp32
    if (w == 0) {
        float s_ = 0.f;
#pragma unroll
        for (int ww = 0; ww < 8; ++ww) s_ += pl[ww * 64 + l];
        l_run = l_run * a_prev + s_;
        lrun_s[l] = l_run;
    }
    __syncthreads();
#pragma unroll
    for (int qf = 0; qf < 4; ++qf) {
        float rl = 1.0f / lrun_s[qf * 16 + lr];
#pragma unroll
        for (int df = 0; df < 8; ++df) {
            f32x4 v = o[qf][df] * rl;
            float* dst = Out + (((b << 12) + q0 + qf * 16 + lr) << 10) + w * 128 + df * 16 + lg * 4;
            *(f32x4*)dst = v;
        }
    }
}

// ---------------------------------------------------------------------------
extern "C" void kernel_launch(void* const* d_in, const int* in_sizes, int n_in,
                              void* d_out, int out_size, void* d_ws, size_t ws_size,
                              hipStream_t stream) {
    const float* x  = (const float*)d_in[0];
    const float* Wq = (const float*)d_in[1];
    const float* Wk = (const float*)d_in[2];
    const float* Wv = (const float*)d_in[3];
    float* out = (float*)d_out;

    char* ws = (char*)d_ws;
    u16* Wt = (u16*)(ws);                               //  6,291,456 B
    u16* Q  = (u16*)(ws + 6291456);                     // 33,554,432 B
    u16* K  = (u16*)(ws + 6291456 + 33554432);          // 33,554,432 B
    u16* Vt = (u16*)(ws + 6291456 + 2 * 33554432);      // 33,554,432 B  (total ~102 MB)

    wt_kernel<<<dim3(16, 16, 3), 256, 0, stream>>>(Wq, Wk, Wv, Wt);
    qkv_gemm<<<dim3(3072), 256, 0, stream>>>(x, Wt, Q, K, Vt);
    attn_kernel<<<dim3(256), 512, 0, stream>>>(Q, K, Vt, out);
}

// Round 2
// 915.495 us; speedup vs baseline: 1.1674x; 1.1674x over previous
//
#include <hip/hip_runtime.h>

typedef unsigned short u16;
typedef float f32x4 __attribute__((ext_vector_type(4)));
typedef u16   u16x4 __attribute__((ext_vector_type(4)));
typedef u16   u16x8 __attribute__((ext_vector_type(8)));
typedef __bf16 bf16x8 __attribute__((ext_vector_type(8)));

static __device__ __forceinline__ u16 f2bf(float x) {
    unsigned int u = __builtin_bit_cast(unsigned int, x);
    u = (u + 0x7FFFu + ((u >> 16) & 1u)) >> 16;
    return (u16)u;
}
static __device__ __forceinline__ bf16x8 as_bf(u16x8 v) { return __builtin_bit_cast(bf16x8, v); }

// ---------------------------------------------------------------------------
// Kernel 1: W [1024 d_in][1024 d_out] fp32  ->  Wt [mat][1024 d_out][1024 d_in] bf16
// ---------------------------------------------------------------------------
__global__ __launch_bounds__(256) void wt_kernel(const float* __restrict__ Wq,
                                                 const float* __restrict__ Wk,
                                                 const float* __restrict__ Wv,
                                                 u16* __restrict__ Wt) {
    __shared__ float tile[64][65];
    const int mat = blockIdx.z;
    const float* W = (mat == 0) ? Wq : ((mat == 1) ? Wk : Wv);
    const int bx = blockIdx.x, by = blockIdx.y;
    const int tid = threadIdx.x;
#pragma unroll
    for (int i = 0; i < 16; ++i) {
        int idx = i * 256 + tid;
        int r = idx >> 6, c = idx & 63;
        tile[r][c] = W[(by * 64 + r) * 1024 + bx * 64 + c];
    }
    __syncthreads();
#pragma unroll
    for (int i = 0; i < 16; ++i) {
        int idx = i * 256 + tid;
        int r = idx >> 6, c = idx & 63;
        Wt[mat * 1048576 + (bx * 64 + r) * 1024 + by * 64 + c] = f2bf(tile[c][r]);
    }
}

// ---------------------------------------------------------------------------
// Kernel 2: QKV GEMM (unchanged this round).
// ---------------------------------------------------------------------------
__global__ __launch_bounds__(256, 3) void qkv_gemm(const float* __restrict__ X,
                                                   const u16* __restrict__ Wt,
                                                   u16* __restrict__ Qo,
                                                   u16* __restrict__ Ko,
                                                   u16* __restrict__ Vto) {
    __shared__ u16 As[128 * 64];
    __shared__ u16 Bs[128 * 64];
    const int bid = blockIdx.x;
    const int swz = (bid & 7) * 384 + (bid >> 3);
    const int bm = swz / 24, bn = swz % 24;
    const int tid = threadIdx.x;
    const int w = tid >> 6, l = tid & 63, lg = l >> 4, lr = l & 15;
    const int wr = w >> 1, wc = w & 1;

    const f32x4 z4 = {0.f, 0.f, 0.f, 0.f};
    f32x4 acc[4][4];
#pragma unroll
    for (int m = 0; m < 4; ++m)
#pragma unroll
        for (int n = 0; n < 4; ++n) acc[m][n] = z4;

    for (int kb = 0; kb < 16; ++kb) {
        __syncthreads();
#pragma unroll
        for (int i = 0; i < 4; ++i) {
            int cid = i * 256 + tid;
            int row = cid >> 3, c8 = cid & 7;
            const float* src = X + (bm * 128 + row) * 1024 + kb * 64 + c8 * 8;
            f32x4 v0 = *(const f32x4*)(src);
            f32x4 v1 = *(const f32x4*)(src + 4);
            u16x8 t;
            t[0] = f2bf(v0[0]); t[1] = f2bf(v0[1]); t[2] = f2bf(v0[2]); t[3] = f2bf(v0[3]);
            t[4] = f2bf(v1[0]); t[5] = f2bf(v1[1]); t[6] = f2bf(v1[2]); t[7] = f2bf(v1[3]);
            *(u16x8*)(&As[row * 64 + ((c8 ^ (row & 7)) << 3)]) = t;
        }
#pragma unroll
        for (int i = 0; i < 4; ++i) {
            int cid = i * 256 + tid;
            int row = cid >> 3, c8 = cid & 7;
            u16x8 v = *(const u16x8*)(Wt + (bn * 128 + row) * 1024 + kb * 64 + c8 * 8);
            *(u16x8*)(&Bs[row * 64 + ((c8 ^ (row & 7)) << 3)]) = v;
        }
        __syncthreads();
#pragma unroll
        for (int kk = 0; kk < 2; ++kk) {
            bf16x8 af[4], bfr[4];
#pragma unroll
            for (int m = 0; m < 4; ++m) {
                int row = wr * 64 + m * 16 + lr;
                af[m] = as_bf(*(const u16x8*)(&As[row * 64 + (((kk * 4 + lg) ^ (lr & 7)) << 3)]));
            }
#pragma unroll
            for (int n = 0; n < 4; ++n) {
                int row = wc * 64 + n * 16 + lr;
                bfr[n] = as_bf(*(const u16x8*)(&Bs[row * 64 + (((kk * 4 + lg) ^ (lr & 7)) << 3)]));
            }
#pragma unroll
            for (int m = 0; m < 4; ++m)
#pragma unroll
                for (int n = 0; n < 4; ++n)
                    acc[m][n] = __builtin_amdgcn_mfma_f32_16x16x32_bf16(af[m], bfr[n], acc[m][n], 0, 0, 0);
        }
    }
    const int row0 = bm * 128 + wr * 64;
    const int col0 = bn * 128 + wc * 64;
#pragma unroll
    for (int m = 0; m < 4; ++m) {
#pragma unroll
        for (int n = 0; n < 4; ++n) {
            int col = col0 + n * 16 + lr;
            int mat = col >> 10;
            int cg = col & 1023;
            int row = row0 + m * 16 + lg * 4;
            if (mat == 2) {
                int b = row >> 12, s = row & 4095;
                u16x4 v;
                v[0] = f2bf(acc[m][n][0]); v[1] = f2bf(acc[m][n][1]);
                v[2] = f2bf(acc[m][n][2]); v[3] = f2bf(acc[m][n][3]);
                *(u16x4*)(Vto + b * 4194304 + cg * 4096 + s) = v;
            } else {
                u16* P = mat ? Ko : Qo;
#pragma unroll
                for (int r = 0; r < 4; ++r) P[(row + r) * 1024 + cg] = f2bf(acc[m][n][r]);
            }
        }
    }
}

// ---------------------------------------------------------------------------
// Kernel 3: flash attention, 16 waves (1024 thr), QBLK=64, KVBLK=256.
// Wave w owns 16 keys (k0 + w*16 .. +16) for QK^T; owns d-slice [w*64, w*64+64)
// for PV. P handed off via a 64x128 half-buffer: waves 0-7 write, PV pass A;
// waves 8-15 write (held in regs across pass A), PV pass B.
// ---------------------------------------------------------------------------
__global__ __launch_bounds__(1024, 4) void attn_kernel(const u16* __restrict__ Qg,
                                                       const u16* __restrict__ Kg,
                                                       const u16* __restrict__ Vtg,
                                                       float* __restrict__ Out) {
    __shared__ u16 q_lds[64 * 1024];   // 128 KB, XOR-swizzled rows
    __shared__ u16 p_lds[64 * 128];    // 16 KB half-buffer, XOR-swizzled rows
    __shared__ float pm[16 * 64];      // 4 KB
    __shared__ float pl[16 * 64];      // 4 KB
    __shared__ float mnew_s[64];
    __shared__ float alph_s[64];
    __shared__ float lrun_s[64];
    __shared__ int flag_s;

    const int bid0 = blockIdx.x;
    const int bid = (bid0 & 7) * 32 + (bid0 >> 3);   // XCD chunk swizzle (256 wgs, bijective)
    const int b = bid >> 6, qt = bid & 63;
    const int q0 = qt * 64;
    const int tid = threadIdx.x;
    const int w = tid >> 6, l = tid & 63, lg = l >> 4, lr = l & 15;
    const int wk = w & 7;

    // stage Q tile (once per block), swizzled
#pragma unroll
    for (int i = 0; i < 8; ++i) {
        int cid = i * 1024 + tid;
        int row = cid >> 7, ch = cid & 127;
        u16x8 v = *(const u16x8*)(Qg + (((b << 12) + q0 + row) << 10) + ch * 8);
        *(u16x8*)(&q_lds[(row << 10) + ((ch ^ (row & 7)) << 3)]) = v;
    }

    const f32x4 z4 = {0.f, 0.f, 0.f, 0.f};
    f32x4 o[4][4];
#pragma unroll
    for (int qf = 0; qf < 4; ++qf)
#pragma unroll
        for (int df = 0; df < 4; ++df) o[qf][df] = z4;

    float m_run = -1e30f, l_run = 0.f, a_prev = 1.f;  // wave 0, lane l <-> q row l
    const float kscale = 0.045084220027780106f;       // log2(e)/32

    __syncthreads();

    for (int t = 0; t < 16; ++t) {
        const int k0 = t << 8;
        if (w == 0 && t > 0) {
            float s_ = 0.f;
#pragma unroll
            for (int ww = 0; ww < 16; ++ww) s_ += pl[ww * 64 + l];
            l_run = l_run * a_prev + s_;
        }
        // ---- S^T = K * Q^T (wave's 16 keys x 64 q), pipelined K loads ----
        f32x4 sacc[4] = {z4, z4, z4, z4};
        const u16* kptr = Kg + (((b << 12) + k0 + w * 16 + lr) << 10) + lg * 8;
        bf16x8 kr[2][2];
#pragma unroll
        for (int i = 0; i < 2; ++i) kr[0][i] = *(const bf16x8*)(kptr + i * 32);
#pragma unroll
        for (int c = 0; c < 16; ++c) {
            if (c < 15) {
#pragma unroll
                for (int i = 0; i < 2; ++i)
                    kr[(c + 1) & 1][i] = *(const bf16x8*)(kptr + ((c + 1) * 2 + i) * 32);
            }
#pragma unroll
            for (int i = 0; i < 2; ++i) {
                const int kb = c * 2 + i;
                bf16x8 a = kr[c & 1][i];
#pragma unroll
                for (int qf = 0; qf < 4; ++qf) {
                    int row = qf * 16 + lr;
                    bf16x8 bq = as_bf(*(const u16x8*)(&q_lds[(row << 10) + (((kb * 4 + lg) ^ (row & 7)) << 3)]));
                    sacc[qf] = __builtin_amdgcn_mfma_f32_16x16x32_bf16(a, bq, sacc[qf], 0, 0, 0);
                }
            }
        }
        float sp[4][4];
#pragma unroll
        for (int qf = 0; qf < 4; ++qf)
#pragma unroll
            for (int r = 0; r < 4; ++r) sp[qf][r] = sacc[qf][r] * kscale;

        // per-wave partial max per q
#pragma unroll
        for (int qf = 0; qf < 4; ++qf) {
            float v = fmaxf(fmaxf(sp[qf][0], sp[qf][1]), fmaxf(sp[qf][2], sp[qf][3]));
            v = fmaxf(v, __shfl_xor(v, 16, 64));
            v = fmaxf(v, __shfl_xor(v, 32, 64));
            if (lg == 0) pm[w * 64 + qf * 16 + lr] = v;
        }
        __syncthreads();
        if (w == 0) {
            float mt = pm[l];
#pragma unroll
            for (int ww = 1; ww < 16; ++ww) mt = fmaxf(mt, pm[ww * 64 + l]);
            bool resc = mt > m_run + 11.5f;   // defer-max (8 nats, log2 domain)
            float mn = resc ? mt : m_run;
            float al = resc ? exp2f(m_run - mn) : 1.0f;
            mnew_s[l] = mn;
            alph_s[l] = al;
            m_run = mn;
            a_prev = al;
            unsigned long long bb = __ballot(al != 1.0f);
            if (l == 0) flag_s = (bb != 0ull) ? 1 : 0;
        }
        __syncthreads();
        const int fl = flag_s;
        u16x4 pk[4];
#pragma unroll
        for (int qf = 0; qf < 4; ++qf) {
            const int q = qf * 16 + lr;
            float mn = mnew_s[q];
            float p0 = exp2f(sp[qf][0] - mn);
            float p1 = exp2f(sp[qf][1] - mn);
            float p2 = exp2f(sp[qf][2] - mn);
            float p3 = exp2f(sp[qf][3] - mn);
            float sv = (p0 + p1) + (p2 + p3);
            sv += __shfl_xor(sv, 16, 64);
            sv += __shfl_xor(sv, 32, 64);
            if (lg == 0) pl[w * 64 + qf * 16 + lr] = sv;
            pk[qf][0] = f2bf(p0); pk[qf][1] = f2bf(p1); pk[qf][2] = f2bf(p2); pk[qf][3] = f2bf(p3);
            if (w < 8) {
                int byteoff = (q << 8) + ((wk * 32 + lg * 8) ^ ((q & 7) << 4));
                *(u16x4*)((char*)p_lds + byteoff) = pk[qf];
            }
            if (fl) {
                float al = alph_s[q];
#pragma unroll
                for (int df = 0; df < 4; ++df) o[qf][df] *= al;
            }
        }
        __syncthreads();
        // ---- PV pass A: keys k0 .. k0+127 ----
        const u16* vbase = Vtg + b * 4194304 + k0;
#pragma unroll
        for (int ks = 0; ks < 4; ++ks) {
            bf16x8 av[4];
#pragma unroll
            for (int df = 0; df < 4; ++df)
                av[df] = *(const bf16x8*)(vbase + (w * 64 + df * 16 + lr) * 4096 + ks * 32 + lg * 8);
#pragma unroll
            for (int qf = 0; qf < 4; ++qf) {
                const int q = qf * 16 + lr;
                bf16x8 bp = as_bf(*(const u16x8*)((char*)p_lds + (q << 8) + ((ks * 64 + lg * 16) ^ ((q & 7) << 4))));
#pragma unroll
                for (int df = 0; df < 4; ++df)
                    o[qf][df] = __builtin_amdgcn_mfma_f32_16x16x32_bf16(av[df], bp, o[qf][df], 0, 0, 0);
            }
        }
        __syncthreads();
        // waves 8-15 publish their P
        if (w >= 8) {
#pragma unroll
            for (int qf = 0; qf < 4; ++qf) {
                const int q = qf * 16 + lr;
                int byteoff = (q << 8) + ((wk * 32 + lg * 8) ^ ((q & 7) << 4));
                *(u16x4*)((char*)p_lds + byteoff) = pk[qf];
            }
        }
        __syncthreads();
        // ---- PV pass B: keys k0+128 .. k0+255 ----
        const u16* vbase2 = vbase + 128;
#pragma unroll
        for (int ks = 0; ks < 4; ++ks) {
            bf16x8 av[4];
#pragma unroll
            for (int df = 0; df < 4; ++df)
                av[df] = *(const bf16x8*)(vbase2 + (w * 64 + df * 16 + lr) * 4096 + ks * 32 + lg * 8);
#pragma unroll
            for (int qf = 0; qf < 4; ++qf) {
                const int q = qf * 16 + lr;
                bf16x8 bp = as_bf(*(const u16x8*)((char*)p_lds + (q << 8) + ((ks * 64 + lg * 16) ^ ((q & 7) << 4))));
#pragma unroll
                for (int df = 0; df < 4; ++df)
                    o[qf][df] = __builtin_amdgcn_mfma_f32_16x16x32_bf16(av[df], bp, o[qf][df], 0, 0, 0);
            }
        }
        // next-tile p_lds writes are separated from these reads by the
        // pm-barrier and wave0-barrier of tile t+1 -> no extra barrier here.
    }
    // epilogue
    if (w == 0) {
        float s_ = 0.f;
#pragma unroll
        for (int ww = 0; ww < 16; ++ww) s_ += pl[ww * 64 + l];
        l_run = l_run * a_prev + s_;
        lrun_s[l] = l_run;
    }
    __syncthreads();
#pragma unroll
    for (int qf = 0; qf < 4; ++qf) {
        float rl = 1.0f / lrun_s[qf * 16 + lr];
#pragma unroll
        for (int df = 0; df < 4; ++df) {
            f32x4 v = o[qf][df] * rl;
            float* dst = Out + (((b << 12) + q0 + qf * 16 + lr) << 10) + w * 64 + df * 16 + lg * 4;
            *(f32x4*)dst = v;
        }
    }
}

// ---------------------------------------------------------------------------
extern "C" void kernel_launch(void* const* d_in, const int* in_sizes, int n_in,
                              void* d_out, int out_size, void* d_ws, size_t ws_size,
                              hipStream_t stream) {
    const float* x  = (const float*)d_in[0];
    const float* Wq = (const float*)d_in[1];
    const float* Wk = (const float*)d_in[2];
    const float* Wv = (const float*)d_in[3];
    float* out = (float*)d_out;

    char* ws = (char*)d_ws;
    u16* Wt = (u16*)(ws);
    u16* Q  = (u16*)(ws + 6291456);
    u16* K  = (u16*)(ws + 6291456 + 33554432);
    u16* Vt = (u16*)(ws + 6291456 + 2 * 33554432);

    wt_kernel<<<dim3(16, 16, 3), 256, 0, stream>>>(Wq, Wk, Wv, Wt);
    qkv_gemm<<<dim3(3072), 256, 0, stream>>>(x, Wt, Q, K, Vt);
    attn_kernel<<<dim3(256), 1024, 0, stream>>>(Q, K, Vt, out);
}

// Round 3
// 782.576 us; speedup vs baseline: 1.3657x; 1.1698x over previous
//
#include <hip/hip_runtime.h>

typedef unsigned short u16;
typedef float f32x4 __attribute__((ext_vector_type(4)));
typedef u16   u16x4 __attribute__((ext_vector_type(4)));
typedef u16   u16x8 __attribute__((ext_vector_type(8)));
typedef __bf16 bf16x8 __attribute__((ext_vector_type(8)));

static __device__ __forceinline__ u16 f2bf(float x) {
    unsigned int u = __builtin_bit_cast(unsigned int, x);
    u = (u + 0x7FFFu + ((u >> 16) & 1u)) >> 16;
    return (u16)u;
}
static __device__ __forceinline__ bf16x8 as_bf(u16x8 v) { return __builtin_bit_cast(bf16x8, v); }

// ---------------------------------------------------------------------------
// Kernel 1: W [1024 d_in][1024 d_out] fp32  ->  Wt [mat][1024 d_out][1024 d_in] bf16
// ---------------------------------------------------------------------------
__global__ __launch_bounds__(256) void wt_kernel(const float* __restrict__ Wq,
                                                 const float* __restrict__ Wk,
                                                 const float* __restrict__ Wv,
                                                 u16* __restrict__ Wt) {
    __shared__ float tile[64][65];
    const int mat = blockIdx.z;
    const float* W = (mat == 0) ? Wq : ((mat == 1) ? Wk : Wv);
    const int bx = blockIdx.x, by = blockIdx.y;
    const int tid = threadIdx.x;
#pragma unroll
    for (int i = 0; i < 16; ++i) {
        int idx = i * 256 + tid;
        int r = idx >> 6, c = idx & 63;
        tile[r][c] = W[(by * 64 + r) * 1024 + bx * 64 + c];
    }
    __syncthreads();
#pragma unroll
    for (int i = 0; i < 16; ++i) {
        int idx = i * 256 + tid;
        int r = idx >> 6, c = idx & 63;
        Wt[mat * 1048576 + (bx * 64 + r) * 1024 + by * 64 + c] = f2bf(tile[c][r]);
    }
}

// ---------------------------------------------------------------------------
// Kernel 2: QKV GEMM. Q row-major bf16 [16384][1024].
// K tiled:  Kt[b][s>>4][d>>5][16 ki][32 di]   (A-frag-ready 16x32 subtiles)
// V tiled:  Vt[b][d>>4][k>>5][16 di][32 ki]   (A-frag-ready 16x32 subtiles of V^T)
// ---------------------------------------------------------------------------
__global__ __launch_bounds__(256, 3) void qkv_gemm(const float* __restrict__ X,
                                                   const u16* __restrict__ Wt,
                                                   u16* __restrict__ Qo,
                                                   u16* __restrict__ Kt,
                                                   u16* __restrict__ Vt) {
    __shared__ u16 As[128 * 64];
    __shared__ u16 Bs[128 * 64];
    const int bid = blockIdx.x;
    const int swz = (bid & 7) * 384 + (bid >> 3);
    const int bm = swz / 24, bn = swz % 24;
    const int tid = threadIdx.x;
    const int w = tid >> 6, l = tid & 63, lg = l >> 4, lr = l & 15;
    const int wr = w >> 1, wc = w & 1;

    const f32x4 z4 = {0.f, 0.f, 0.f, 0.f};
    f32x4 acc[4][4];
#pragma unroll
    for (int m = 0; m < 4; ++m)
#pragma unroll
        for (int n = 0; n < 4; ++n) acc[m][n] = z4;

    for (int kb = 0; kb < 16; ++kb) {
        __syncthreads();
#pragma unroll
        for (int i = 0; i < 4; ++i) {
            int cid = i * 256 + tid;
            int row = cid >> 3, c8 = cid & 7;
            const float* src = X + (bm * 128 + row) * 1024 + kb * 64 + c8 * 8;
            f32x4 v0 = *(const f32x4*)(src);
            f32x4 v1 = *(const f32x4*)(src + 4);
            u16x8 t;
            t[0] = f2bf(v0[0]); t[1] = f2bf(v0[1]); t[2] = f2bf(v0[2]); t[3] = f2bf(v0[3]);
            t[4] = f2bf(v1[0]); t[5] = f2bf(v1[1]); t[6] = f2bf(v1[2]); t[7] = f2bf(v1[3]);
            *(u16x8*)(&As[row * 64 + ((c8 ^ (row & 7)) << 3)]) = t;
        }
#pragma unroll
        for (int i = 0; i < 4; ++i) {
            int cid = i * 256 + tid;
            int row = cid >> 3, c8 = cid & 7;
            u16x8 v = *(const u16x8*)(Wt + (bn * 128 + row) * 1024 + kb * 64 + c8 * 8);
            *(u16x8*)(&Bs[row * 64 + ((c8 ^ (row & 7)) << 3)]) = v;
        }
        __syncthreads();
#pragma unroll
        for (int kk = 0; kk < 2; ++kk) {
            bf16x8 af[4], bfr[4];
#pragma unroll
            for (int m = 0; m < 4; ++m) {
                int row = wr * 64 + m * 16 + lr;
                af[m] = as_bf(*(const u16x8*)(&As[row * 64 + (((kk * 4 + lg) ^ (lr & 7)) << 3)]));
            }
#pragma unroll
            for (int n = 0; n < 4; ++n) {
                int row = wc * 64 + n * 16 + lr;
                bfr[n] = as_bf(*(const u16x8*)(&Bs[row * 64 + (((kk * 4 + lg) ^ (lr & 7)) << 3)]));
            }
#pragma unroll
            for (int m = 0; m < 4; ++m)
#pragma unroll
                for (int n = 0; n < 4; ++n)
                    acc[m][n] = __builtin_amdgcn_mfma_f32_16x16x32_bf16(af[m], bfr[n], acc[m][n], 0, 0, 0);
        }
    }
    const int row0 = bm * 128 + wr * 64;
    const int col0 = bn * 128 + wc * 64;
#pragma unroll
    for (int m = 0; m < 4; ++m) {
#pragma unroll
        for (int n = 0; n < 4; ++n) {
            int col = col0 + n * 16 + lr;
            int mat = col >> 10;
            int cg = col & 1023;
            int row = row0 + m * 16 + lg * 4;   // 4 consecutive seq rows r=0..3
            int b = row >> 12, s = row & 4095;
            if (mat == 2) {
                // V tiled: Vt[b][cg>>4][s>>5][cg&15][s&31], [16 di][32 ki] row-major
                u16x4 v;
                v[0] = f2bf(acc[m][n][0]); v[1] = f2bf(acc[m][n][1]);
                v[2] = f2bf(acc[m][n][2]); v[3] = f2bf(acc[m][n][3]);
                int off = (((b * 64 + (cg >> 4)) * 128) + (s >> 5)) * 512 + (cg & 15) * 32 + (s & 31);
                *(u16x4*)(Vt + off) = v;
            } else if (mat == 1) {
                // K tiled: Kt[b][s>>4][cg>>5][s&15][cg&31], [16 ki][32 di] row-major
                int base = (((b * 256 + (s >> 4)) * 32) + (cg >> 5)) * 512 + (cg & 31);
#pragma unroll
                for (int r = 0; r < 4; ++r)
                    Kt[base + ((s & 15) + r) * 32] = f2bf(acc[m][n][r]);
            } else {
#pragma unroll
                for (int r = 0; r < 4; ++r) Qo[(row + r) * 1024 + cg] = f2bf(acc[m][n][r]);
            }
        }
    }
}

// ---------------------------------------------------------------------------
// Kernel 3: flash attention, 16 waves, QBLK=64, KVBLK=256.
// K and V^T read from frag-ready 16x32 tiles: each wave load = one contiguous
// 1KB block (lane l reads bytes [(l&15)*64 + (l>>4)*16, +16) of the tile).
// ---------------------------------------------------------------------------
__global__ __launch_bounds__(1024, 4) void attn_kernel(const u16* __restrict__ Qg,
                                                       const u16* __restrict__ Kt,
                                                       const u16* __restrict__ Vt,
                                                       float* __restrict__ Out) {
    __shared__ u16 q_lds[64 * 1024];   // 128 KB, XOR-swizzled rows
    __shared__ u16 p_lds[64 * 128];    // 16 KB half-buffer
    __shared__ float pm[16 * 64];
    __shared__ float pl[16 * 64];
    __shared__ float mnew_s[64];
    __shared__ float alph_s[64];
    __shared__ float lrun_s[64];
    __shared__ int flag_s;

    const int bid0 = blockIdx.x;
    const int bid = (bid0 & 7) * 32 + (bid0 >> 3);   // XCD chunk swizzle
    const int b = bid >> 6, qt = bid & 63;
    const int q0 = qt * 64;
    const int tid = threadIdx.x;
    const int w = tid >> 6, l = tid & 63, lg = l >> 4, lr = l & 15;
    const int wk = w & 7;
    const int perm = lr * 32 + lg * 8;               // lane offset within a 16x32 tile

    // stage Q tile (once per block), swizzled
#pragma unroll
    for (int i = 0; i < 8; ++i) {
        int cid = i * 1024 + tid;
        int row = cid >> 7, ch = cid & 127;
        u16x8 v = *(const u16x8*)(Qg + (((b << 12) + q0 + row) << 10) + ch * 8);
        *(u16x8*)(&q_lds[(row << 10) + ((ch ^ (row & 7)) << 3)]) = v;
    }

    const f32x4 z4 = {0.f, 0.f, 0.f, 0.f};
    f32x4 o[4][4];
#pragma unroll
    for (int qf = 0; qf < 4; ++qf)
#pragma unroll
        for (int df = 0; df < 4; ++df) o[qf][df] = z4;

    float m_run = -1e30f, l_run = 0.f, a_prev = 1.f;  // wave 0, lane l <-> q row l
    const float kscale = 0.045084220027780106f;       // log2(e)/32

    __syncthreads();

    for (int t = 0; t < 16; ++t) {
        if (w == 0 && t > 0) {
            float s_ = 0.f;
#pragma unroll
            for (int ww = 0; ww < 16; ++ww) s_ += pl[ww * 64 + l];
            l_run = l_run * a_prev + s_;
        }
        // ---- S^T = K * Q^T : wave's 16 keys (kg = t*16+w), coalesced tiled K loads ----
        f32x4 sacc[4] = {z4, z4, z4, z4};
        const u16* kbase = Kt + (b * 256 + t * 16 + w) * 16384 + perm;
        bf16x8 kr0 = *(const bf16x8*)(kbase);
        bf16x8 kr1 = *(const bf16x8*)(kbase + 512);
#pragma unroll
        for (int kp = 0; kp < 16; ++kp) {
            bf16x8 a0 = kr0, a1 = kr1;
            if (kp < 15) {
                kr0 = *(const bf16x8*)(kbase + (2 * kp + 2) * 512);
                kr1 = *(const bf16x8*)(kbase + (2 * kp + 3) * 512);
            }
#pragma unroll
            for (int qf = 0; qf < 4; ++qf) {
                int row = qf * 16 + lr;
                bf16x8 bq = as_bf(*(const u16x8*)(&q_lds[(row << 10) + ((((2 * kp) * 4 + lg) ^ (row & 7)) << 3)]));
                sacc[qf] = __builtin_amdgcn_mfma_f32_16x16x32_bf16(a0, bq, sacc[qf], 0, 0, 0);
            }
#pragma unroll
            for (int qf = 0; qf < 4; ++qf) {
                int row = qf * 16 + lr;
                bf16x8 bq = as_bf(*(const u16x8*)(&q_lds[(row << 10) + ((((2 * kp + 1) * 4 + lg) ^ (row & 7)) << 3)]));
                sacc[qf] = __builtin_amdgcn_mfma_f32_16x16x32_bf16(a1, bq, sacc[qf], 0, 0, 0);
            }
        }
        // scale in place; per-wave partial max per q
#pragma unroll
        for (int qf = 0; qf < 4; ++qf) {
            sacc[qf] *= kscale;
            float v = fmaxf(fmaxf(sacc[qf][0], sacc[qf][1]), fmaxf(sacc[qf][2], sacc[qf][3]));
            v = fmaxf(v, __shfl_xor(v, 16, 64));
            v = fmaxf(v, __shfl_xor(v, 32, 64));
            if (lg == 0) pm[w * 64 + qf * 16 + lr] = v;
        }
        __syncthreads();
        if (w == 0) {
            float mt = pm[l];
#pragma unroll
            for (int ww = 1; ww < 16; ++ww) mt = fmaxf(mt, pm[ww * 64 + l]);
            bool resc = mt > m_run + 11.5f;   // defer-max (8 nats, log2 domain)
            float mn = resc ? mt : m_run;
            float al = resc ? exp2f(m_run - mn) : 1.0f;
            mnew_s[l] = mn;
            alph_s[l] = al;
            m_run = mn;
            a_prev = al;
            unsigned long long bb = __ballot(al != 1.0f);
            if (l == 0) flag_s = (bb != 0ull) ? 1 : 0;
        }
        __syncthreads();
        const int fl = flag_s;
        u16x4 pk[4];
#pragma unroll
        for (int qf = 0; qf < 4; ++qf) {
            const int q = qf * 16 + lr;
            float mn = mnew_s[q];
            float p0 = exp2f(sacc[qf][0] - mn);
            float p1 = exp2f(sacc[qf][1] - mn);
            float p2 = exp2f(sacc[qf][2] - mn);
            float p3 = exp2f(sacc[qf][3] - mn);
            float sv = (p0 + p1) + (p2 + p3);
            sv += __shfl_xor(sv, 16, 64);
            sv += __shfl_xor(sv, 32, 64);
            if (lg == 0) pl[w * 64 + qf * 16 + lr] = sv;
            pk[qf][0] = f2bf(p0); pk[qf][1] = f2bf(p1); pk[qf][2] = f2bf(p2); pk[qf][3] = f2bf(p3);
            if (w < 8) {
                int byteoff = (q << 8) + ((wk * 32 + lg * 8) ^ ((q & 7) << 4));
                *(u16x4*)((char*)p_lds + byteoff) = pk[qf];
            }
            if (fl) {
                float al = alph_s[q];
#pragma unroll
                for (int df = 0; df < 4; ++df) o[qf][df] *= al;
            }
        }
        __syncthreads();
        // ---- PV pass A: keys t*256 .. +127 (kg = t*8 .. t*8+3) ----
        const u16* vbase = Vt + ((b * 64 + w * 4) * 128 + t * 8) * 512 + perm;
#pragma unroll
        for (int ks = 0; ks < 4; ++ks) {
            bf16x8 av[4];
#pragma unroll
            for (int df = 0; df < 4; ++df)
                av[df] = *(const bf16x8*)(vbase + (df * 128 + ks) * 512);
#pragma unroll
            for (int qf = 0; qf < 4; ++qf) {
                const int q = qf * 16 + lr;
                bf16x8 bp = as_bf(*(const u16x8*)((char*)p_lds + (q << 8) + ((ks * 64 + lg * 16) ^ ((q & 7) << 4))));
#pragma unroll
                for (int df = 0; df < 4; ++df)
                    o[qf][df] = __builtin_amdgcn_mfma_f32_16x16x32_bf16(av[df], bp, o[qf][df], 0, 0, 0);
            }
        }
        __syncthreads();
        if (w >= 8) {
#pragma unroll
            for (int qf = 0; qf < 4; ++qf) {
                const int q = qf * 16 + lr;
                int byteoff = (q << 8) + ((wk * 32 + lg * 8) ^ ((q & 7) << 4));
                *(u16x4*)((char*)p_lds + byteoff) = pk[qf];
            }
        }
        __syncthreads();
        // ---- PV pass B: keys t*256+128 .. +255 (kg = t*8+4 .. t*8+7) ----
#pragma unroll
        for (int ks = 0; ks < 4; ++ks) {
            bf16x8 av[4];
#pragma unroll
            for (int df = 0; df < 4; ++df)
                av[df] = *(const bf16x8*)(vbase + (df * 128 + 4 + ks) * 512);
#pragma unroll
            for (int qf = 0; qf < 4; ++qf) {
                const int q = qf * 16 + lr;
                bf16x8 bp = as_bf(*(const u16x8*)((char*)p_lds + (q << 8) + ((ks * 64 + lg * 16) ^ ((q & 7) << 4))));
#pragma unroll
                for (int df = 0; df < 4; ++df)
                    o[qf][df] = __builtin_amdgcn_mfma_f32_16x16x32_bf16(av[df], bp, o[qf][df], 0, 0, 0);
            }
        }
    }
    // epilogue
    if (w == 0) {
        float s_ = 0.f;
#pragma unroll
        for (int ww = 0; ww < 16; ++ww) s_ += pl[ww * 64 + l];
        l_run = l_run * a_prev + s_;
        lrun_s[l] = l_run;
    }
    __syncthreads();
#pragma unroll
    for (int qf = 0; qf < 4; ++qf) {
        float rl = 1.0f / lrun_s[qf * 16 + lr];
#pragma unroll
        for (int df = 0; df < 4; ++df) {
            f32x4 v = o[qf][df] * rl;
            float* dst = Out + (((b << 12) + q0 + qf * 16 + lr) << 10) + w * 64 + df * 16 + lg * 4;
            *(f32x4*)dst = v;
        }
    }
}

// ---------------------------------------------------------------------------
extern "C" void kernel_launch(void* const* d_in, const int* in_sizes, int n_in,
                              void* d_out, int out_size, void* d_ws, size_t ws_size,
                              hipStream_t stream) {
    const float* x  = (const float*)d_in[0];
    const float* Wq = (const float*)d_in[1];
    const float* Wk = (const float*)d_in[2];
    const float* Wv = (const float*)d_in[3];
    float* out = (float*)d_out;

    char* ws = (char*)d_ws;
    u16* Wt = (u16*)(ws);
    u16* Q  = (u16*)(ws + 6291456);
    u16* Kt = (u16*)(ws + 6291456 + 33554432);
    u16* Vt = (u16*)(ws + 6291456 + 2 * 33554432);

    wt_kernel<<<dim3(16, 16, 3), 256, 0, stream>>>(Wq, Wk, Wv, Wt);
    qkv_gemm<<<dim3(3072), 256, 0, stream>>>(x, Wt, Q, Kt, Vt);
    attn_kernel<<<dim3(256), 1024, 0, stream>>>(Q, Kt, Vt, out);
}

// Round 4
// 669.157 us; speedup vs baseline: 1.5971x; 1.1695x over previous
//
#include <hip/hip_runtime.h>

typedef unsigned short u16;
typedef float f32x4 __attribute__((ext_vector_type(4)));
typedef float f32x16 __attribute__((ext_vector_type(16)));
typedef u16   u16x4 __attribute__((ext_vector_type(4)));
typedef u16   u16x8 __attribute__((ext_vector_type(8)));
typedef __bf16 bf16x8 __attribute__((ext_vector_type(8)));

static __device__ __forceinline__ u16 f2bf(float x) {
    unsigned int u = __builtin_bit_cast(unsigned int, x);
    u = (u + 0x7FFFu + ((u >> 16) & 1u)) >> 16;
    return (u16)u;
}
static __device__ __forceinline__ bf16x8 as_bf(u16x8 v) { return __builtin_bit_cast(bf16x8, v); }
static __device__ __forceinline__ f32x16 zero16() {
    f32x16 z;
#pragma unroll
    for (int i = 0; i < 16; ++i) z[i] = 0.f;
    return z;
}

// ---------------------------------------------------------------------------
// Kernel 1: W [1024 d_in][1024 d_out] fp32  ->  Wt [mat][1024 d_out][1024 d_in] bf16
// ---------------------------------------------------------------------------
__global__ __launch_bounds__(256) void wt_kernel(const float* __restrict__ Wq,
                                                 const float* __restrict__ Wk,
                                                 const float* __restrict__ Wv,
                                                 u16* __restrict__ Wt) {
    __shared__ float tile[64][65];
    const int mat = blockIdx.z;
    const float* W = (mat == 0) ? Wq : ((mat == 1) ? Wk : Wv);
    const int bx = blockIdx.x, by = blockIdx.y;
    const int tid = threadIdx.x;
#pragma unroll
    for (int i = 0; i < 16; ++i) {
        int idx = i * 256 + tid;
        int r = idx >> 6, c = idx & 63;
        tile[r][c] = W[(by * 64 + r) * 1024 + bx * 64 + c];
    }
    __syncthreads();
#pragma unroll
    for (int i = 0; i < 16; ++i) {
        int idx = i * 256 + tid;
        int r = idx >> 6, c = idx & 63;
        Wt[mat * 1048576 + (bx * 64 + r) * 1024 + by * 64 + c] = f2bf(tile[c][r]);
    }
}

// ---------------------------------------------------------------------------
// Kernel 2: QKV GEMM. Q row-major bf16 [16384][1024].
// K frag-tiled for 32x32x16 A-operand: Kt[b][key>>5][d>>4][frag 512 u16],
//   frag u16 idx = (d>>3 &1)*256 + (key&31)*8 + (d&7)   (lane l reads l*8..+8)
// V frag-tiled for 16x16x32 A-operand (unchanged):
//   Vt[b][d>>4][key>>5][frag 512 u16], idx = (d&15)*32 + (key&31)
// ---------------------------------------------------------------------------
__global__ __launch_bounds__(256, 3) void qkv_gemm(const float* __restrict__ X,
                                                   const u16* __restrict__ Wt,
                                                   u16* __restrict__ Qo,
                                                   u16* __restrict__ Kt,
                                                   u16* __restrict__ Vt) {
    __shared__ u16 As[128 * 64];
    __shared__ u16 Bs[128 * 64];
    const int bid = blockIdx.x;
    const int swz = (bid & 7) * 384 + (bid >> 3);
    const int bm = swz / 24, bn = swz % 24;
    const int tid = threadIdx.x;
    const int w = tid >> 6, l = tid & 63, lg = l >> 4, lr = l & 15;
    const int wr = w >> 1, wc = w & 1;

    const f32x4 z4 = {0.f, 0.f, 0.f, 0.f};
    f32x4 acc[4][4];
#pragma unroll
    for (int m = 0; m < 4; ++m)
#pragma unroll
        for (int n = 0; n < 4; ++n) acc[m][n] = z4;

    for (int kb = 0; kb < 16; ++kb) {
        __syncthreads();
#pragma unroll
        for (int i = 0; i < 4; ++i) {
            int cid = i * 256 + tid;
            int row = cid >> 3, c8 = cid & 7;
            const float* src = X + (bm * 128 + row) * 1024 + kb * 64 + c8 * 8;
            f32x4 v0 = *(const f32x4*)(src);
            f32x4 v1 = *(const f32x4*)(src + 4);
            u16x8 t;
            t[0] = f2bf(v0[0]); t[1] = f2bf(v0[1]); t[2] = f2bf(v0[2]); t[3] = f2bf(v0[3]);
            t[4] = f2bf(v1[0]); t[5] = f2bf(v1[1]); t[6] = f2bf(v1[2]); t[7] = f2bf(v1[3]);
            *(u16x8*)(&As[row * 64 + ((c8 ^ (row & 7)) << 3)]) = t;
        }
#pragma unroll
        for (int i = 0; i < 4; ++i) {
            int cid = i * 256 + tid;
            int row = cid >> 3, c8 = cid & 7;
            u16x8 v = *(const u16x8*)(Wt + (bn * 128 + row) * 1024 + kb * 64 + c8 * 8);
            *(u16x8*)(&Bs[row * 64 + ((c8 ^ (row & 7)) << 3)]) = v;
        }
        __syncthreads();
#pragma unroll
        for (int kk = 0; kk < 2; ++kk) {
            bf16x8 af[4], bfr[4];
#pragma unroll
            for (int m = 0; m < 4; ++m) {
                int row = wr * 64 + m * 16 + lr;
                af[m] = as_bf(*(const u16x8*)(&As[row * 64 + (((kk * 4 + lg) ^ (lr & 7)) << 3)]));
            }
#pragma unroll
            for (int n = 0; n < 4; ++n) {
                int row = wc * 64 + n * 16 + lr;
                bfr[n] = as_bf(*(const u16x8*)(&Bs[row * 64 + (((kk * 4 + lg) ^ (lr & 7)) << 3)]));
            }
#pragma unroll
            for (int m = 0; m < 4; ++m)
#pragma unroll
                for (int n = 0; n < 4; ++n)
                    acc[m][n] = __builtin_amdgcn_mfma_f32_16x16x32_bf16(af[m], bfr[n], acc[m][n], 0, 0, 0);
        }
    }
    const int row0 = bm * 128 + wr * 64;
    const int col0 = bn * 128 + wc * 64;
#pragma unroll
    for (int m = 0; m < 4; ++m) {
#pragma unroll
        for (int n = 0; n < 4; ++n) {
            int col = col0 + n * 16 + lr;
            int mat = col >> 10;
            int cg = col & 1023;
            int row = row0 + m * 16 + lg * 4;   // 4 consecutive seq rows r=0..3
            int b = row >> 12, s = row & 4095;
            if (mat == 2) {
                // V frag-tiled (16x16x32 A): idx = (d&15)*32 + (key&31)
                u16x4 v;
                v[0] = f2bf(acc[m][n][0]); v[1] = f2bf(acc[m][n][1]);
                v[2] = f2bf(acc[m][n][2]); v[3] = f2bf(acc[m][n][3]);
                int off = (((b * 64 + (cg >> 4)) * 128) + (s >> 5)) * 512 + (cg & 15) * 32 + (s & 31);
                *(u16x4*)(Vt + off) = v;
            } else if (mat == 1) {
                // K frag-tiled (32x32x16 A): idx = (d>>3&1)*256 + (key&31)*8 + (d&7)
                int base = ((b * 128 + (s >> 5)) * 64 + (cg >> 4)) * 512
                         + ((cg >> 3) & 1) * 256 + (s & 31) * 8 + (cg & 7);
#pragma unroll
                for (int r = 0; r < 4; ++r)
                    Kt[base + r * 8] = f2bf(acc[m][n][r]);
            } else {
#pragma unroll
                for (int r = 0; r < 4; ++r) Qo[(row + r) * 1024 + cg] = f2bf(acc[m][n][r]);
            }
        }
    }
}

// ---------------------------------------------------------------------------
// Kernel 3: flash attention, 16 waves, QBLK=64, KVBLK=512.
// QK^T: 32x32x16 MFMA, wave owns 32 keys; Q staged in LDS in B-frag-linear
// order (conflict-free linear ds_read); K A-frags linear from global.
// PV: 16x16x32 (unchanged layouts), 4 quarter-passes of 128 keys through
// the 16KB p_lds buffer.
// ---------------------------------------------------------------------------
__global__ __launch_bounds__(1024, 4) void attn_kernel(const u16* __restrict__ Qg,
                                                       const u16* __restrict__ Kt,
                                                       const u16* __restrict__ Vt,
                                                       float* __restrict__ Out) {
    __shared__ u16 q_lds[128 * 512];   // 128 B-frags x 1KB, frag-linear
    __shared__ u16 p_lds[64 * 128];    // 16 KB quarter buffer (128 keys)
    __shared__ float pm[16 * 64];
    __shared__ float pl[16 * 64];
    __shared__ float mnew_s[64];
    __shared__ float alph_s[64];
    __shared__ float lrun_s[64];
    __shared__ int flag_s;

    const int bid0 = blockIdx.x;
    const int bid = (bid0 & 7) * 32 + (bid0 >> 3);   // XCD chunk swizzle
    const int b = bid >> 6, qt = bid & 63;
    const int q0 = qt * 64;
    const int tid = threadIdx.x;
    const int w = tid >> 6, l = tid & 63, lg = l >> 4, lr = l & 15;
    const int l5 = l & 31, h = l >> 5;
    const int perm = lr * 32 + lg * 8;               // lane offset in a V frag

    // stage Q into B-frag-linear layout: frag(qf,kb) holds
    // Q[q0+qf*32+(l&31)][kb*16+(l>>5)*8 .. +8] at frag*512 + l*8
#pragma unroll
    for (int i = 0; i < 8; ++i) {
        int frag = i * 16 + w;
        int qf = frag >> 6, kb = frag & 63;
        u16x8 v = *(const u16x8*)(Qg + (((b << 12) + q0 + qf * 32 + l5) << 10) + kb * 16 + h * 8);
        *(u16x8*)(&q_lds[frag * 512 + l * 8]) = v;
    }

    const f32x4 z4 = {0.f, 0.f, 0.f, 0.f};
    f32x4 o[4][4];
#pragma unroll
    for (int qf = 0; qf < 4; ++qf)
#pragma unroll
        for (int df = 0; df < 4; ++df) o[qf][df] = z4;

    float m_run = -1e30f, l_run = 0.f, a_prev = 1.f;  // wave 0, lane l <-> q row l
    const float kscale = 0.045084220027780106f;       // log2(e)/32

#define PUBLISH() do {                                                         \
    int w4_ = w & 3;                                                           \
    _Pragma("unroll") for (int qf_ = 0; qf_ < 2; ++qf_)                        \
    _Pragma("unroll") for (int rp_ = 0; rp_ < 8; ++rp_) {                      \
        int r_ = rp_ * 2;                                                      \
        int keyb_ = w4_ * 32 + (r_ & 3) + 4 * h + 8 * (r_ >> 2);               \
        int q_ = qf_ * 32 + l5;                                                \
        int off_ = (q_ << 8) + ((keyb_ * 2) ^ ((q_ & 7) << 4));                \
        *(unsigned int*)((char*)p_lds + off_) = pk[qf_ * 8 + rp_];             \
    } } while (0)

    __syncthreads();

    for (int t = 0; t < 8; ++t) {
        // ---- S^T = K * Q^T : 32x32x16, wave's 32 keys (group t*16+w) ----
        f32x16 sacc[2];
        sacc[0] = zero16(); sacc[1] = zero16();
        const u16* kbase = Kt + (size_t)((b * 128 + t * 16 + w) * 64) * 512 + l * 8;
        bf16x8 ka = *(const bf16x8*)(kbase);
#pragma unroll
        for (int kb = 0; kb < 64; ++kb) {
            bf16x8 a = ka;
            if (kb < 63) ka = *(const bf16x8*)(kbase + (kb + 1) * 512);
            bf16x8 b0 = as_bf(*(const u16x8*)(&q_lds[kb * 512 + l * 8]));
            sacc[0] = __builtin_amdgcn_mfma_f32_32x32x16_bf16(a, b0, sacc[0], 0, 0, 0);
            bf16x8 b1 = as_bf(*(const u16x8*)(&q_lds[(64 + kb) * 512 + l * 8]));
            sacc[1] = __builtin_amdgcn_mfma_f32_32x32x16_bf16(a, b1, sacc[1], 0, 0, 0);
        }
        // scale + per-wave per-q max (q = qf*32 + l5; keys spread over regs & halves)
#pragma unroll
        for (int qf = 0; qf < 2; ++qf) {
            sacc[qf] = sacc[qf] * kscale;
            float mx = sacc[qf][0];
#pragma unroll
            for (int r = 1; r < 16; ++r) mx = fmaxf(mx, sacc[qf][r]);
            mx = fmaxf(mx, __shfl_xor(mx, 32, 64));
            if (l < 32) pm[w * 64 + qf * 32 + l] = mx;
        }
        __syncthreads();
        if (w == 0) {
            if (t > 0) {
                float s_ = 0.f;
#pragma unroll
                for (int ww = 0; ww < 16; ++ww) s_ += pl[ww * 64 + l];
                l_run = l_run * a_prev + s_;
            }
            float mt = pm[l];
#pragma unroll
            for (int ww = 1; ww < 16; ++ww) mt = fmaxf(mt, pm[ww * 64 + l]);
            bool resc = mt > m_run + 11.5f;   // defer-max (8 nats, log2 domain)
            float mn = resc ? mt : m_run;
            float al = resc ? exp2f(m_run - mn) : 1.0f;
            mnew_s[l] = mn;
            alph_s[l] = al;
            m_run = mn;
            a_prev = al;
            unsigned long long bb = __ballot(al != 1.0f);
            if (l == 0) flag_s = (bb != 0ull) ? 1 : 0;
        }
        __syncthreads();
        const int fl = flag_s;
        unsigned int pk[16];
#pragma unroll
        for (int qf = 0; qf < 2; ++qf) {
            float mn = mnew_s[qf * 32 + l5];
            float sum = 0.f;
            float p[16];
#pragma unroll
            for (int r = 0; r < 16; ++r) { p[r] = exp2f(sacc[qf][r] - mn); sum += p[r]; }
            sum += __shfl_xor(sum, 32, 64);
            if (l < 32) pl[w * 64 + qf * 32 + l] = sum;
#pragma unroll
            for (int rp = 0; rp < 8; ++rp)
                pk[qf * 8 + rp] = (unsigned int)f2bf(p[rp * 2]) | ((unsigned int)f2bf(p[rp * 2 + 1]) << 16);
        }
        if (fl) {
#pragma unroll
            for (int qf = 0; qf < 4; ++qf) {
                float al = alph_s[qf * 16 + lr];
#pragma unroll
                for (int df = 0; df < 4; ++df) o[qf][df] *= al;
            }
        }
        if (w < 4) PUBLISH();
        __syncthreads();
        // ---- PV: 4 quarter-passes of 128 keys, 16x16x32 (layouts unchanged) ----
#pragma unroll
        for (int qtr = 0; qtr < 4; ++qtr) {
            const u16* vbase = Vt + (((b * 64 + w * 4) * 128) + (t * 16 + qtr * 4)) * 512 + perm;
#pragma unroll
            for (int ks = 0; ks < 4; ++ks) {
                bf16x8 av[4];
#pragma unroll
                for (int df = 0; df < 4; ++df)
                    av[df] = *(const bf16x8*)(vbase + (df * 128 + ks) * 512);
#pragma unroll
                for (int qf = 0; qf < 4; ++qf) {
                    const int q = qf * 16 + lr;
                    bf16x8 bp = as_bf(*(const u16x8*)((char*)p_lds + (q << 8) + ((ks * 64 + lg * 16) ^ ((q & 7) << 4))));
#pragma unroll
                    for (int df = 0; df < 4; ++df)
                        o[qf][df] = __builtin_amdgcn_mfma_f32_16x16x32_bf16(av[df], bp, o[qf][df], 0, 0, 0);
                }
            }
            if (qtr < 3) {
                __syncthreads();
                if ((w >> 2) == qtr + 1) PUBLISH();
                __syncthreads();
            }
        }
        // next tile's p_lds writes are fenced by the pm/softmax barriers
    }
    // epilogue
    if (w == 0) {
        float s_ = 0.f;
#pragma unroll
        for (int ww = 0; ww < 16; ++ww) s_ += pl[ww * 64 + l];
        l_run = l_run * a_prev + s_;
        lrun_s[l] = l_run;
    }
    __syncthreads();
#pragma unroll
    for (int qf = 0; qf < 4; ++qf) {
        float rl = 1.0f / lrun_s[qf * 16 + lr];
#pragma unroll
        for (int df = 0; df < 4; ++df) {
            f32x4 v = o[qf][df] * rl;
            float* dst = Out + (((b << 12) + q0 + qf * 16 + lr) << 10) + w * 64 + df * 16 + lg * 4;
            *(f32x4*)dst = v;
        }
    }
#undef PUBLISH
}

// ---------------------------------------------------------------------------
extern "C" void kernel_launch(void* const* d_in, const int* in_sizes, int n_in,
                              void* d_out, int out_size, void* d_ws, size_t ws_size,
                              hipStream_t stream) {
    const float* x  = (const float*)d_in[0];
    const float* Wq = (const float*)d_in[1];
    const float* Wk = (const float*)d_in[2];
    const float* Wv = (const float*)d_in[3];
    float* out = (float*)d_out;

    char* ws = (char*)d_ws;
    u16* Wt = (u16*)(ws);
    u16* Q  = (u16*)(ws + 6291456);
    u16* Kt = (u16*)(ws + 6291456 + 33554432);
    u16* Vt = (u16*)(ws + 6291456 + 2 * 33554432);

    wt_kernel<<<dim3(16, 16, 3), 256, 0, stream>>>(Wq, Wk, Wv, Wt);
    qkv_gemm<<<dim3(3072), 256, 0, stream>>>(x, Wt, Q, Kt, Vt);
    attn_kernel<<<dim3(256), 1024, 0, stream>>>(Q, Kt, Vt, out);
}